// Round 3
// baseline (312.787 us; speedup 1.0000x reference)
//
#include <hip/hip_runtime.h>
#include <math.h>

// Problem constants (fixed by reference):
// B=2, L=2048, D=2048, H=16, G=4, HD=128, EPS=1e-6, scale = 1/HD^2 = 1/16384
#define SEQ 2048
#define DMODEL 2048
#define NHQ 16
#define NHK 4

typedef __attribute__((ext_vector_type(8))) short short8;
typedef __attribute__((ext_vector_type(8))) unsigned short ushort8;
typedef __attribute__((ext_vector_type(4))) float floatx4;

__device__ __forceinline__ unsigned short f2bf(float f) {
  unsigned int u = __builtin_bit_cast(unsigned int, f);
  u += 0x7fffu + ((u >> 16) & 1u);   // round-to-nearest-even
  return (unsigned short)(u >> 16);
}
__device__ __forceinline__ float bf2f(unsigned short s) {
  unsigned int u = ((unsigned int)s) << 16;
  return __builtin_bit_cast(float, u);
}

// ---------------------------------------------------------------------------
// One prep launch: cast x -> bf16 AND all 4 weight transposes.
// 64-row transpose tiles: every output row written as ushort8 (16B/lane);
// x-cast uses 16B loads+stores.
// grid (64, 32, 4), block (32,8).
// ---------------------------------------------------------------------------
__global__ __launch_bounds__(256) void prep(const float* __restrict__ x,
                                            const float* __restrict__ Wq,
                                            const float* __restrict__ Wk,
                                            const float* __restrict__ Wv,
                                            const float* __restrict__ Wo,
                                            unsigned short* __restrict__ x_bf,
                                            unsigned short* __restrict__ wqkv_t,
                                            unsigned short* __restrict__ wo_t) {
  const int z = blockIdx.z;
  const int tx = threadIdx.x, ty = threadIdx.y;
  const int tid = ty * 32 + tx;
  if (z == 3) {
    const size_t base = ((size_t)(blockIdx.y * 64 + blockIdx.x)) * 4096 + (size_t)tid * 16;
    const float4 v0 = *(const float4*)(x + base);
    const float4 v1 = *(const float4*)(x + base + 4);
    const float4 v2 = *(const float4*)(x + base + 8);
    const float4 v3 = *(const float4*)(x + base + 12);
    ushort8 w0, w1;
    w0[0] = f2bf(v0.x); w0[1] = f2bf(v0.y); w0[2] = f2bf(v0.z); w0[3] = f2bf(v0.w);
    w0[4] = f2bf(v1.x); w0[5] = f2bf(v1.y); w0[6] = f2bf(v1.z); w0[7] = f2bf(v1.w);
    w1[0] = f2bf(v2.x); w1[1] = f2bf(v2.y); w1[2] = f2bf(v2.z); w1[3] = f2bf(v2.w);
    w1[4] = f2bf(v3.x); w1[5] = f2bf(v3.y); w1[6] = f2bf(v3.z); w1[7] = f2bf(v3.w);
    *(ushort8*)(x_bf + base) = w0;
    *(ushort8*)(x_bf + base + 8) = w1;
    return;
  }
  int bx = blockIdx.x;
  const float* in;
  unsigned short* out;
  int C;
  const int R = 2048;
  if (z == 0)      { in = Wq; out = wqkv_t;                          C = 2048; }
  else if (z == 1) { in = Wo; out = wo_t;                            C = 2048; }
  else {
    if (bx < 16)      { in = Wk; out = wqkv_t + (size_t)2048 * 2048; C = 512; }
    else if (bx < 32) { in = Wv; out = wqkv_t + (size_t)2560 * 2048; C = 512; bx -= 16; }
    else return;
  }
  __shared__ float tile[32][65];
  const int c0 = bx * 32, r0 = blockIdx.y * 64;
#pragma unroll
  for (int j = 0; j < 8; ++j)
    tile[tx][ty + j * 8] = in[(size_t)(r0 + ty + j * 8) * C + c0 + tx];
  __syncthreads();
  const int c = tid >> 3;          // output row (= input col) 0..31
  const int l8 = tid & 7;          // 8-lane segment within the 64-row span
  ushort8 w;
#pragma unroll
  for (int u = 0; u < 8; ++u) w[u] = f2bf(tile[c][l8 * 8 + u]);
  *(ushort8*)(out + (size_t)(c0 + c) * R + r0 + l8 * 8) = w;
}

// ---------------------------------------------------------------------------
// 4-wave GEMM helpers (128x128 tile, 256 threads, 64x64 per wave).
// R11: m97 geometry (acc[4][4] -> 32 FLOP per LDS-byte-read, vs 21.3 for
// R10's 64x32/wave: per block-K-step ds_read drops 48KB -> 32KB, MFMA per
// read doubles) COMBINED with R9 dbuf and R10 XOR swizzle.
// Staging: SOURCE chunk is XOR-pre-swizzled (LDS dest of global_load_lds
// must stay linear; swizzle lives in the global address + read address):
//   LDS[row][chunk] holds global[row][chunk ^ ((row>>1)&3)]   (chunk = 16B)
// stage row = rowa + (lane>>2), rowa % 16 == 0  ->  source chunk
// (lane&3) ^ ((lane>>3)&3). Read row = wr*64+i*16+m15 -> read chunk
// quad ^ ((m15>>1)&3). Bank-start = 16*(m15&1)+4*(quad^(m15>>1)): 8
// starts x 2 lanes = 2-way = free (m136; was 8-way, 6.68M cyc in R0/R1).
// ---------------------------------------------------------------------------
__device__ __forceinline__ void stage_tile4(const unsigned short* __restrict__ A,
                                            const unsigned short* __restrict__ Bt,
                                            unsigned short* As, unsigned short* Bs,
                                            int bm, int bn, int K, int k0,
                                            int wave, int srow, int scol) {
#pragma unroll
  for (int it = 0; it < 2; ++it) {
    const int rowa = wave * 32 + it * 16;
    const unsigned short* ga = A + (size_t)(bm + rowa + srow) * K + k0 + scol;
    const unsigned short* gb = Bt + (size_t)(bn + rowa + srow) * K + k0 + scol;
    __builtin_amdgcn_global_load_lds(
        (const __attribute__((address_space(1))) void*)ga,
        (__attribute__((address_space(3))) void*)&As[rowa * 32], 16, 0, 0);
    __builtin_amdgcn_global_load_lds(
        (const __attribute__((address_space(1))) void*)gb,
        (__attribute__((address_space(3))) void*)&Bs[rowa * 32], 16, 0, 0);
  }
}

__device__ __forceinline__ void mfma_tile4(const unsigned short* As, const unsigned short* Bs,
                                           floatx4 (&acc)[4][4],
                                           int wr, int wc, int m15, int quad) {
  const int co = ((quad ^ ((m15 >> 1) & 3)) * 8);   // swizzled 16B chunk
  short8 af[4], bfr[4];
  const unsigned short* pa = &As[(wr * 64 + m15) * 32 + co];
  const unsigned short* pb = &Bs[(wc * 64 + m15) * 32 + co];
#pragma unroll
  for (int i = 0; i < 4; ++i) af[i] = *(const short8*)(pa + i * 16 * 32);
#pragma unroll
  for (int j = 0; j < 4; ++j) bfr[j] = *(const short8*)(pb + j * 16 * 32);
#pragma unroll
  for (int i = 0; i < 4; ++i)
#pragma unroll
    for (int j = 0; j < 4; ++j)
      acc[i][j] = __builtin_amdgcn_mfma_f32_16x16x32_bf16(af[i], bfr[j], acc[i][j], 0, 0, 0);
}

// ---------------------------------------------------------------------------
// Fused QKV GEMM + RMSNorm + RoPE + V-transpose.
// R11: 4 waves x 64x64/wave (m97 geometry) + dbuf 2-phase + swizzle.
// Each 128-col block tile is exactly one head: bx<16 Q, 16..19 K, 20..23 V.
// ---------------------------------------------------------------------------
__global__ __launch_bounds__(256) void gemm_qkv_fused(const unsigned short* __restrict__ A,
                                                      const unsigned short* __restrict__ Bt,
                                                      unsigned short* __restrict__ qout,
                                                      unsigned short* __restrict__ kout,
                                                      unsigned short* __restrict__ vout,
                                                      const float* __restrict__ q_scale,
                                                      const float* __restrict__ k_scale,
                                                      const float* __restrict__ cosb,
                                                      const float* __restrict__ sinb) {
  __shared__ unsigned short smem[128 * 129];   // 33 KB; first 32 KB = staging dbuf
  unsigned short* As0 = smem;
  unsigned short* Bs0 = smem + 4096;
  unsigned short* As1 = smem + 8192;
  unsigned short* Bs1 = smem + 12288;

  const int tid = threadIdx.x;
  const int wave = tid >> 6;
  const int lane = tid & 63;
  const int bm = blockIdx.y * 128;
  const int bx = blockIdx.x;            // head-block 0..23
  const int bn = bx * 128;
  const int wr = wave >> 1;
  const int wc = wave & 1;
  const int m15 = lane & 15;
  const int quad = lane >> 4;

  floatx4 acc[4][4];
#pragma unroll
  for (int i = 0; i < 4; ++i)
#pragma unroll
    for (int j = 0; j < 4; ++j) acc[i][j] = (floatx4){0.f, 0.f, 0.f, 0.f};

  const int srow = lane >> 2;
  const int scol = (((lane & 3) ^ ((lane >> 3) & 3))) * 8;   // pre-swizzled source chunk

  stage_tile4(A, Bt, As0, Bs0, bm, bn, 2048, 0, wave, srow, scol);
  __syncthreads();

  for (int k0 = 0; k0 < 2048; k0 += 64) {
    stage_tile4(A, Bt, As1, Bs1, bm, bn, 2048, k0 + 32, wave, srow, scol);
    mfma_tile4(As0, Bs0, acc, wr, wc, m15, quad);
    __syncthreads();                       // As1/Bs1 landed; As0/Bs0 reads done
    if (k0 + 64 < 2048)
      stage_tile4(A, Bt, As0, Bs0, bm, bn, 2048, k0 + 64, wave, srow, scol);
    mfma_tile4(As1, Bs1, acc, wr, wc, m15, quad);
    __syncthreads();                       // As0/Bs0 landed; As1/Bs1 reads done
  }

  // ---- phase 1: acc -> padded bf16 LDS tile (stride 129 halfwords).
#pragma unroll
  for (int i = 0; i < 4; ++i)
#pragma unroll
    for (int j = 0; j < 4; ++j) {
      const int col = wc * 64 + j * 16 + m15;
#pragma unroll
      for (int reg = 0; reg < 4; ++reg) {
        const int row = wr * 64 + i * 16 + quad * 4 + reg;
        smem[row * 129 + col] = f2bf(acc[i][j][reg]);
      }
    }
  __syncthreads();

  // ---- phase 2: per-head epilogue (4 waves x 32 rows each).
  const int t = tid & 63;
  const int wv = tid >> 6;
  const int b = bm >> 11;
  const int l_base = bm & (SEQ - 1);

  if (bx < 20) {
    const float* scale = (bx < NHQ) ? q_scale : k_scale;
    unsigned short* dstbase = (bx < NHQ)
        ? qout + ((size_t)(b * NHQ + bx) * SEQ + l_base) * 128
        : kout + ((size_t)(b * NHK + (bx - NHQ)) * SEQ + l_base) * 128;
    const float sc0 = scale[t];
    const float sc1 = scale[t + 64];
#pragma unroll 4
    for (int rr = 0; rr < 32; ++rr) {
      const int row = wv * 32 + rr;
      const float v0 = bf2f(smem[row * 129 + t]);
      const float v1 = bf2f(smem[row * 129 + t + 64]);
      float ss = v0 * v0 + v1 * v1;
#pragma unroll
      for (int m = 1; m < 64; m <<= 1) ss += __shfl_xor(ss, m);
      const float r = rsqrtf(ss * (1.0f / 128.0f) + 1e-6f);
      const int l = l_base + row;
      const float c0 = cosb[(size_t)l * 128 + t];
      const float s0 = sinb[(size_t)l * 128 + t];
      const float c1 = cosb[(size_t)l * 128 + t + 64];
      const float s1 = sinb[(size_t)l * 128 + t + 64];
      const float a0 = v0 * r * sc0;
      const float a1 = v1 * r * sc1;
      unsigned short* dst = dstbase + (size_t)row * 128;
      dst[t]      = f2bf(a0 * c0 - a1 * s0);
      dst[t + 64] = f2bf(a1 * c1 + a0 * s1);
    }
  } else {
    const int g = bx - 20;
    unsigned short* vbase = vout + (size_t)(b * NHK + g) * 128 * SEQ + l_base;
#pragma unroll 4
    for (int dd = 0; dd < 32; ++dd) {
      const int d = wv * 32 + dd;
      unsigned short* dst = vbase + (size_t)d * SEQ;
      dst[t]      = smem[t * 129 + d];
      dst[t + 64] = smem[(t + 64) * 129 + d];
    }
  }
}

// ---------------------------------------------------------------------------
// bf16 MFMA GEMM: C = A @ B, fp32 out (used for Wo).
// R11: same 4-wave 64x64/wave + dbuf + swizzle structure.
// ---------------------------------------------------------------------------
__global__ __launch_bounds__(256) void gemm_bf16_f32(const unsigned short* __restrict__ A,
                                                     const unsigned short* __restrict__ Bt,
                                                     float* __restrict__ C,
                                                     int M, int N, int K) {
  __shared__ unsigned short smem[4 * 128 * 32];  // 32 KB staging dbuf
  unsigned short* As0 = smem;
  unsigned short* Bs0 = smem + 4096;
  unsigned short* As1 = smem + 8192;
  unsigned short* Bs1 = smem + 12288;

  const int tid = threadIdx.x;
  const int wave = tid >> 6;
  const int lane = tid & 63;
  const int bm = blockIdx.y * 128;
  const int bn = blockIdx.x * 128;
  const int wr = wave >> 1;
  const int wc = wave & 1;
  const int m15 = lane & 15;
  const int quad = lane >> 4;

  floatx4 acc[4][4];
#pragma unroll
  for (int i = 0; i < 4; ++i)
#pragma unroll
    for (int j = 0; j < 4; ++j) acc[i][j] = (floatx4){0.f, 0.f, 0.f, 0.f};

  const int srow = lane >> 2;
  const int scol = (((lane & 3) ^ ((lane >> 3) & 3))) * 8;

  stage_tile4(A, Bt, As0, Bs0, bm, bn, K, 0, wave, srow, scol);
  __syncthreads();

  for (int k0 = 0; k0 < K; k0 += 64) {
    stage_tile4(A, Bt, As1, Bs1, bm, bn, K, k0 + 32, wave, srow, scol);
    mfma_tile4(As0, Bs0, acc, wr, wc, m15, quad);
    __syncthreads();
    if (k0 + 64 < K)
      stage_tile4(A, Bt, As0, Bs0, bm, bn, K, k0 + 64, wave, srow, scol);
    mfma_tile4(As1, Bs1, acc, wr, wc, m15, quad);
    __syncthreads();
  }

#pragma unroll
  for (int i = 0; i < 4; ++i)
#pragma unroll
    for (int j = 0; j < 4; ++j) {
      const int col = bn + wc * 64 + j * 16 + m15;
#pragma unroll
      for (int reg = 0; reg < 4; ++reg) {
        const int row = bm + wr * 64 + i * 16 + quad * 4 + reg;
        C[(size_t)row * N + col] = acc[i][j][reg];
      }
    }
}

// ---------------------------------------------------------------------------
// MFMA flash attention (causal GQA), no-max softmax.
// |s| = |q.k|/16384 <= 128/16384 by Cauchy-Schwarz (rms-normed q,k, unit
// scales, norm-preserving RoPE) -> exp(s) can't overflow; no running max.
// Ps aliased over Ks (Ks dead after QK, Ps born after): LDS 42 -> 32 KB.
// __launch_bounds__(256, 4): VGPR cap 128 >= the ~68 this kernel needs ->
// 4 blocks/CU with NO spill.
// R8 lesson: (256,5) capped VGPR at ~102, allocator went to 48 and spilled
// acc_o to scratch (WRITE_SIZE 16->114 MB, 2.2x slower). R5 lesson: BM=128
// spills likewise. The live set (8 acc_o + 4 qf + 4 acc_s x4) needs ~128 cap.
// ---------------------------------------------------------------------------
__global__ __launch_bounds__(256, 4) void attn_mfma(const unsigned short* __restrict__ qb,
                                                    const unsigned short* __restrict__ kb,
                                                    const unsigned short* __restrict__ vtb,
                                                    unsigned short* __restrict__ o) {
  __shared__ unsigned short Ks[64 * 128];   // QK phase: K tile; PV phase: Ps (stride 72)
  __shared__ unsigned short Vs[128 * 64];
  unsigned short* Ps = Ks;

  const int tid = threadIdx.x;
  const int wave = tid >> 6;
  const int lane = tid & 63;
  const int m15 = lane & 15;
  const int quad = lane >> 4;
  const int bh = blockIdx.x;           // 0..31
  const int b = bh >> 4;
  const int h = bh & 15;
  const int g = h >> 2;
  const int q0 = ((int)gridDim.y - 1 - (int)blockIdx.y) * 64;  // longest first

  const unsigned short* qhead = qb + (size_t)bh * SEQ * 128;
  const unsigned short* khead = kb + (size_t)(b * NHK + g) * SEQ * 128;
  const unsigned short* vthead = vtb + (size_t)(b * NHK + g) * 128 * SEQ;

  short8 qf[4];
  {
    const unsigned short* qp = qhead + (size_t)(q0 + wave * 16 + m15) * 128 + quad * 8;
#pragma unroll
    for (int ks = 0; ks < 4; ++ks) qf[ks] = *(const short8*)(qp + ks * 32);
  }

  floatx4 acc_o[8];
#pragma unroll
  for (int n = 0; n < 8; ++n) acc_o[n] = (floatx4){0.f, 0.f, 0.f, 0.f};
  float l_lane[4] = {0.f, 0.f, 0.f, 0.f};
  const float inv_scale = 1.0f / 16384.0f;

  for (int j0 = 0; j0 <= q0; j0 += 64) {
    // ---- stage K tile (64 x 128, chunk-XOR swizzle) and Vt tile (128 x 64)
#pragma unroll
    for (int t = 0; t < 4; ++t) {
      const int r = wave * 16 + t * 4 + (lane >> 4);
      const int cg = (lane & 15) ^ (r & 15);
      const unsigned short* src = khead + (size_t)(j0 + r) * 128 + cg * 8;
      __builtin_amdgcn_global_load_lds(
          (const __attribute__((address_space(1))) void*)src,
          (__attribute__((address_space(3))) void*)&Ks[(wave * 16 + t * 4) * 128], 16, 0, 0);
    }
#pragma unroll
    for (int t = 0; t < 4; ++t) {
      const int d = wave * 32 + t * 8 + (lane >> 3);
      const int cg = (lane & 7) ^ (d & 7);
      const unsigned short* src = vthead + (size_t)d * SEQ + j0 + cg * 8;
      __builtin_amdgcn_global_load_lds(
          (const __attribute__((address_space(1))) void*)src,
          (__attribute__((address_space(3))) void*)&Vs[(wave * 32 + t * 8) * 64], 16, 0, 0);
    }
    __syncthreads();

    // ---- S = Q K^T
    floatx4 acc_s[4];
#pragma unroll
    for (int n = 0; n < 4; ++n) acc_s[n] = (floatx4){0.f, 0.f, 0.f, 0.f};
#pragma unroll
    for (int ks = 0; ks < 4; ++ks) {
#pragma unroll
      for (int n = 0; n < 4; ++n) {
        const short8 bfrag = *(const short8*)&Ks[(n * 16 + m15) * 128 + (((ks * 4 + quad) ^ m15) * 8)];
        acc_s[n] = __builtin_amdgcn_mfma_f32_16x16x32_bf16(qf[ks], bfrag, acc_s[n], 0, 0, 0);
      }
    }
    __syncthreads();   // all waves done reading Ks before Ps overwrites it

    // ---- p = exp(s/16384) -> Ps (over Ks region); mask only diagonal tile.
    if (j0 == q0) {
      const int row_g = wave * 16 + quad * 4;
#pragma unroll
      for (int n = 0; n < 4; ++n) {
        const int col = n * 16 + m15;
#pragma unroll
        for (int rg = 0; rg < 4; ++rg) {
          float p = (col > row_g + rg) ? 0.0f : __expf(acc_s[n][rg] * inv_scale);
          l_lane[rg] += p;
          Ps[(wave * 16 + quad * 4 + rg) * 72 + n * 16 + m15] = f2bf(p);
        }
      }
    } else {
#pragma unroll
      for (int n = 0; n < 4; ++n) {
#pragma unroll
        for (int rg = 0; rg < 4; ++rg) {
          const float p = __expf(acc_s[n][rg] * inv_scale);
          l_lane[rg] += p;
          Ps[(wave * 16 + quad * 4 + rg) * 72 + n * 16 + m15] = f2bf(p);
        }
      }
    }

    // ---- O += P V  (Ps rows wave-private: same-wave write->read, in-order)
#pragma unroll
    for (int kk = 0; kk < 2; ++kk) {
      const short8 a = *(const short8*)&Ps[(wave * 16 + m15) * 72 + kk * 32 + quad * 8];
#pragma unroll
      for (int n = 0; n < 8; ++n) {
        const short8 bfrag = *(const short8*)&Vs[(n * 16 + m15) * 64 + (((kk * 4 + quad) ^ (m15 & 7)) * 8)];
        acc_o[n] = __builtin_amdgcn_mfma_f32_16x16x32_bf16(a, bfrag, acc_o[n], 0, 0, 0);
      }
    }
    __syncthreads();   // Ps reads done before next iteration restages Ks
  }

#pragma unroll
  for (int rg = 0; rg < 4; ++rg) {
    float l = l_lane[rg];
    l += __shfl_xor(l, 1);
    l += __shfl_xor(l, 2);
    l += __shfl_xor(l, 4);
    l += __shfl_xor(l, 8);
    const float invl = 1.0f / l;
    const size_t row = (size_t)(b * SEQ + q0 + wave * 16 + quad * 4 + rg);
#pragma unroll
    for (int n = 0; n < 8; ++n)
      o[row * DMODEL + h * 128 + n * 16 + m15] = f2bf(acc_o[n][rg] * invl);
  }
}

// ---------------------------------------------------------------------------
extern "C" void kernel_launch(void* const* d_in, const int* in_sizes, int n_in,
                              void* d_out, int out_size, void* d_ws, size_t ws_size,
                              hipStream_t stream) {
  const float* x       = (const float*)d_in[0];
  const float* Wq      = (const float*)d_in[1];
  const float* Wk      = (const float*)d_in[2];
  const float* Wv      = (const float*)d_in[3];
  const float* Wo      = (const float*)d_in[4];
  const float* q_scale = (const float*)d_in[5];
  const float* k_scale = (const float*)d_in[6];
  const float* cosb    = (const float*)d_in[7];
  const float* sinb    = (const float*)d_in[8];
  float* out = (float*)d_out;

  // Workspace (79.69 MB, no overlays; 83.9 MB proven available):
  char* w = (char*)d_ws;
  unsigned short* x_bf    = (unsigned short*)w;               // [0, 16.78M)
  unsigned short* wqkv_t  = (unsigned short*)(w + 16777216);  // [16.78M, 29.36M)
  unsigned short* q_bf    = (unsigned short*)(w + 29360128);  // [29.36M, 46.14M)
  unsigned short* k_bf    = (unsigned short*)(w + 46137344);  // [46.14M, 50.33M)
  unsigned short* vt      = (unsigned short*)(w + 50331648);  // [50.33M, 54.53M)
  unsigned short* wo_t    = (unsigned short*)(w + 54525952);  // [54.53M, 62.91M)
  unsigned short* attn_bf = (unsigned short*)(w + 62914560);  // [62.91M, 79.69M)

  // One prep launch: cast x + all weight transposes (64-row tiles).
  prep<<<dim3(64, 32, 4), dim3(32, 8), 0, stream>>>(x, Wq, Wk, Wv, Wo, x_bf, wqkv_t, wo_t);

  // Fused QKV projection + RMSNorm + RoPE + V-transpose (4-wave dbuf+swz).
  gemm_qkv_fused<<<dim3(24, 32), 256, 0, stream>>>(x_bf, wqkv_t, q_bf, k_bf, vt,
                                                   q_scale, k_scale, cosb, sinb);

  // Attention, then output projection (4-wave dbuf+swz).
  attn_mfma<<<dim3(2 * NHQ, SEQ / 64), 256, 0, stream>>>(q_bf, k_bf, vt, attn_bf);
  gemm_bf16_f32<<<dim3(2048 / 128, 4096 / 128), 256, 0, stream>>>(
      attn_bf, wo_t, out, 4096, 2048, 2048);
}

// Round 4
// 305.108 us; speedup vs baseline: 1.0252x; 1.0252x over previous
//
#include <hip/hip_runtime.h>
#include <math.h>

// Problem constants (fixed by reference):
// B=2, L=2048, D=2048, H=16, G=4, HD=128, EPS=1e-6, scale = 1/HD^2 = 1/16384
#define SEQ 2048
#define DMODEL 2048
#define NHQ 16
#define NHK 4

typedef __attribute__((ext_vector_type(8))) short short8;
typedef __attribute__((ext_vector_type(8))) unsigned short ushort8;
typedef __attribute__((ext_vector_type(4))) float floatx4;

__device__ __forceinline__ unsigned short f2bf(float f) {
  unsigned int u = __builtin_bit_cast(unsigned int, f);
  u += 0x7fffu + ((u >> 16) & 1u);   // round-to-nearest-even
  return (unsigned short)(u >> 16);
}
__device__ __forceinline__ float bf2f(unsigned short s) {
  unsigned int u = ((unsigned int)s) << 16;
  return __builtin_bit_cast(float, u);
}

// ---------------------------------------------------------------------------
// One prep launch: cast x -> bf16 AND all 4 weight transposes.
// 64-row transpose tiles: every output row written as ushort8 (16B/lane);
// x-cast uses 16B loads+stores.
// grid (64, 32, 4), block (32,8).
// ---------------------------------------------------------------------------
__global__ __launch_bounds__(256) void prep(const float* __restrict__ x,
                                            const float* __restrict__ Wq,
                                            const float* __restrict__ Wk,
                                            const float* __restrict__ Wv,
                                            const float* __restrict__ Wo,
                                            unsigned short* __restrict__ x_bf,
                                            unsigned short* __restrict__ wqkv_t,
                                            unsigned short* __restrict__ wo_t) {
  const int z = blockIdx.z;
  const int tx = threadIdx.x, ty = threadIdx.y;
  const int tid = ty * 32 + tx;
  if (z == 3) {
    const size_t base = ((size_t)(blockIdx.y * 64 + blockIdx.x)) * 4096 + (size_t)tid * 16;
    const float4 v0 = *(const float4*)(x + base);
    const float4 v1 = *(const float4*)(x + base + 4);
    const float4 v2 = *(const float4*)(x + base + 8);
    const float4 v3 = *(const float4*)(x + base + 12);
    ushort8 w0, w1;
    w0[0] = f2bf(v0.x); w0[1] = f2bf(v0.y); w0[2] = f2bf(v0.z); w0[3] = f2bf(v0.w);
    w0[4] = f2bf(v1.x); w0[5] = f2bf(v1.y); w0[6] = f2bf(v1.z); w0[7] = f2bf(v1.w);
    w1[0] = f2bf(v2.x); w1[1] = f2bf(v2.y); w1[2] = f2bf(v2.z); w1[3] = f2bf(v2.w);
    w1[4] = f2bf(v3.x); w1[5] = f2bf(v3.y); w1[6] = f2bf(v3.z); w1[7] = f2bf(v3.w);
    *(ushort8*)(x_bf + base) = w0;
    *(ushort8*)(x_bf + base + 8) = w1;
    return;
  }
  int bx = blockIdx.x;
  const float* in;
  unsigned short* out;
  int C;
  const int R = 2048;
  if (z == 0)      { in = Wq; out = wqkv_t;                          C = 2048; }
  else if (z == 1) { in = Wo; out = wo_t;                            C = 2048; }
  else {
    if (bx < 16)      { in = Wk; out = wqkv_t + (size_t)2048 * 2048; C = 512; }
    else if (bx < 32) { in = Wv; out = wqkv_t + (size_t)2560 * 2048; C = 512; bx -= 16; }
    else return;
  }
  __shared__ float tile[32][65];
  const int c0 = bx * 32, r0 = blockIdx.y * 64;
#pragma unroll
  for (int j = 0; j < 8; ++j)
    tile[tx][ty + j * 8] = in[(size_t)(r0 + ty + j * 8) * C + c0 + tx];
  __syncthreads();
  const int c = tid >> 3;          // output row (= input col) 0..31
  const int l8 = tid & 7;          // 8-lane segment within the 64-row span
  ushort8 w;
#pragma unroll
  for (int u = 0; u < 8; ++u) w[u] = f2bf(tile[c][l8 * 8 + u]);
  *(ushort8*)(out + (size_t)(c0 + c) * R + r0 + l8 * 8) = w;
}

// ---------------------------------------------------------------------------
// 4-wave GEMM helpers (128x128 tile, 256 threads, 64x64 per wave).
// Staging: SOURCE chunk is XOR-pre-swizzled (LDS dest of global_load_lds
// must stay linear; swizzle lives in the global address + read address):
//   LDS[row][chunk] holds global[row][chunk ^ ((row>>1)&3)]   (chunk = 16B)
// stage row = rowa + (lane>>2), rowa % 16 == 0  ->  source chunk
// (lane&3) ^ ((lane>>3)&3). Read row = wr*64+i*16+m15 -> read chunk
// quad ^ ((m15>>1)&3). Bank-start = 16*(m15&1)+4*(quad^(m15>>1)): 8
// starts x 2 lanes = 2-way = free (m136; was 8-way, 6.68M cyc in R0/R1).
// stage_tile4 = 4 global_load_lds instructions per wave (vmcnt +4).
// ---------------------------------------------------------------------------
__device__ __forceinline__ void stage_tile4(const unsigned short* __restrict__ A,
                                            const unsigned short* __restrict__ Bt,
                                            unsigned short* As, unsigned short* Bs,
                                            int bm, int bn, int K, int k0,
                                            int wave, int srow, int scol) {
#pragma unroll
  for (int it = 0; it < 2; ++it) {
    const int rowa = wave * 32 + it * 16;
    const unsigned short* ga = A + (size_t)(bm + rowa + srow) * K + k0 + scol;
    const unsigned short* gb = Bt + (size_t)(bn + rowa + srow) * K + k0 + scol;
    __builtin_amdgcn_global_load_lds(
        (const __attribute__((address_space(1))) void*)ga,
        (__attribute__((address_space(3))) void*)&As[rowa * 32], 16, 0, 0);
    __builtin_amdgcn_global_load_lds(
        (const __attribute__((address_space(1))) void*)gb,
        (__attribute__((address_space(3))) void*)&Bs[rowa * 32], 16, 0, 0);
  }
}

__device__ __forceinline__ void mfma_tile4(const unsigned short* As, const unsigned short* Bs,
                                           floatx4 (&acc)[4][4],
                                           int wr, int wc, int m15, int quad) {
  const int co = ((quad ^ ((m15 >> 1) & 3)) * 8);   // swizzled 16B chunk
  short8 af[4], bfr[4];
  const unsigned short* pa = &As[(wr * 64 + m15) * 32 + co];
  const unsigned short* pb = &Bs[(wc * 64 + m15) * 32 + co];
#pragma unroll
  for (int i = 0; i < 4; ++i) af[i] = *(const short8*)(pa + i * 16 * 32);
#pragma unroll
  for (int j = 0; j < 4; ++j) bfr[j] = *(const short8*)(pb + j * 16 * 32);
#pragma unroll
  for (int i = 0; i < 4; ++i)
#pragma unroll
    for (int j = 0; j < 4; ++j)
      acc[i][j] = __builtin_amdgcn_mfma_f32_16x16x32_bf16(af[i], bfr[j], acc[i][j], 0, 0, 0);
}

// R12 sync: counted vmcnt + raw barrier (T4, m218). NEVER vmcnt(0) in the
// steady-state loop: tile t+2's 4 loads stay in flight across the barrier;
// only tile t+1's (older, in-order retirement m135) are forced complete.
// "memory" clobber + sched_barrier(0) fence compiler reordering (rule #18).
#define KLOOP_SYNC(cond_deep)                                   \
  do {                                                          \
    if (cond_deep) asm volatile("s_waitcnt vmcnt(4)" ::: "memory"); \
    else           asm volatile("s_waitcnt vmcnt(0)" ::: "memory"); \
    __builtin_amdgcn_s_barrier();                               \
    __builtin_amdgcn_sched_barrier(0);                          \
  } while (0)

// ---------------------------------------------------------------------------
// Fused QKV GEMM + RMSNorm + RoPE + V-transpose.
// R12: 3 rotating staging buffers, prefetch distance 2, counted vmcnt(4)
// sync. R1-R3 matrix showed every 2-buffer variant pinned at 76-78us /
// MfmaUtil 28% -- the __syncthreads() vmcnt(0) drain exposes full load
// latency each of 64 K-steps (~2900cyc/step vs ~240 MFMA + ~580 LDS).
// Race audit: stage at t targets buf[(t+2)%3]=buf[(t-1)%3], last read
// before the barrier ending step t-1 -> no overwrite race; uniform
// branches -> barrier convergence. LDS 48KB -> still 3 blocks/CU (grid cap).
// Each 128-col block tile is exactly one head: bx<16 Q, 16..19 K, 20..23 V.
// ---------------------------------------------------------------------------
__global__ __launch_bounds__(256) void gemm_qkv_fused(const unsigned short* __restrict__ A,
                                                      const unsigned short* __restrict__ Bt,
                                                      unsigned short* __restrict__ qout,
                                                      unsigned short* __restrict__ kout,
                                                      unsigned short* __restrict__ vout,
                                                      const float* __restrict__ q_scale,
                                                      const float* __restrict__ k_scale,
                                                      const float* __restrict__ cosb,
                                                      const float* __restrict__ sinb) {
  __shared__ unsigned short smem[3 * 8192];   // 48 KB: 3 x (As 4096 | Bs 4096) hw
                                              // epilogue reuses first 16512 hw

  const int tid = threadIdx.x;
  const int wave = tid >> 6;
  const int lane = tid & 63;
  const int bm = blockIdx.y * 128;
  const int bx = blockIdx.x;            // head-block 0..23
  const int bn = bx * 128;
  const int wr = wave >> 1;
  const int wc = wave & 1;
  const int m15 = lane & 15;
  const int quad = lane >> 4;

  floatx4 acc[4][4];
#pragma unroll
  for (int i = 0; i < 4; ++i)
#pragma unroll
    for (int j = 0; j < 4; ++j) acc[i][j] = (floatx4){0.f, 0.f, 0.f, 0.f};

  const int srow = lane >> 2;
  const int scol = (((lane & 3) ^ ((lane >> 3) & 3))) * 8;   // pre-swizzled source chunk

  unsigned short* c0 = smem;                // current compute buffer
  unsigned short* c1 = smem + 8192;         // next
  unsigned short* c2 = smem + 16384;        // staging target (t+2)

  // Prologue: stage tiles 0 and 1 (8 loads/wave); force tile 0 complete,
  // leave tile 1's 4 in flight.
  stage_tile4(A, Bt, c0, c0 + 4096, bm, bn, 2048, 0, wave, srow, scol);
  stage_tile4(A, Bt, c1, c1 + 4096, bm, bn, 2048, 32, wave, srow, scol);
  KLOOP_SYNC(true);

  const int NK = 64;                        // 2048 / 32
  for (int t = 0; t < NK; ++t) {
    if (t + 2 < NK)
      stage_tile4(A, Bt, c2, c2 + 4096, bm, bn, 2048, (t + 2) * 32, wave, srow, scol);
    mfma_tile4(c0, c0 + 4096, acc, wr, wc, m15, quad);
    KLOOP_SYNC(t + 2 < NK);                 // forces tile t+1 landed; t+2 flies
    unsigned short* tmp = c0; c0 = c1; c1 = c2; c2 = tmp;
  }

  // ---- phase 1: acc -> padded bf16 LDS tile (stride 129 halfwords).
  // Safe: final KLOOP_SYNC barrier means all waves' K-loop reads are done.
#pragma unroll
  for (int i = 0; i < 4; ++i)
#pragma unroll
    for (int j = 0; j < 4; ++j) {
      const int col = wc * 64 + j * 16 + m15;
#pragma unroll
      for (int reg = 0; reg < 4; ++reg) {
        const int row = wr * 64 + i * 16 + quad * 4 + reg;
        smem[row * 129 + col] = f2bf(acc[i][j][reg]);
      }
    }
  __syncthreads();

  // ---- phase 2: per-head epilogue (4 waves x 32 rows each).
  const int t = tid & 63;
  const int wv = tid >> 6;
  const int b = bm >> 11;
  const int l_base = bm & (SEQ - 1);

  if (bx < 20) {
    const float* scale = (bx < NHQ) ? q_scale : k_scale;
    unsigned short* dstbase = (bx < NHQ)
        ? qout + ((size_t)(b * NHQ + bx) * SEQ + l_base) * 128
        : kout + ((size_t)(b * NHK + (bx - NHQ)) * SEQ + l_base) * 128;
    const float sc0 = scale[t];
    const float sc1 = scale[t + 64];
#pragma unroll 4
    for (int rr = 0; rr < 32; ++rr) {
      const int row = wv * 32 + rr;
      const float v0 = bf2f(smem[row * 129 + t]);
      const float v1 = bf2f(smem[row * 129 + t + 64]);
      float ss = v0 * v0 + v1 * v1;
#pragma unroll
      for (int m = 1; m < 64; m <<= 1) ss += __shfl_xor(ss, m);
      const float r = rsqrtf(ss * (1.0f / 128.0f) + 1e-6f);
      const int l = l_base + row;
      const float c0v = cosb[(size_t)l * 128 + t];
      const float s0 = sinb[(size_t)l * 128 + t];
      const float c1v = cosb[(size_t)l * 128 + t + 64];
      const float s1 = sinb[(size_t)l * 128 + t + 64];
      const float a0 = v0 * r * sc0;
      const float a1 = v1 * r * sc1;
      unsigned short* dst = dstbase + (size_t)row * 128;
      dst[t]      = f2bf(a0 * c0v - a1 * s0);
      dst[t + 64] = f2bf(a1 * c1v + a0 * s1);
    }
  } else {
    const int g = bx - 20;
    unsigned short* vbase = vout + (size_t)(b * NHK + g) * 128 * SEQ + l_base;
#pragma unroll 4
    for (int dd = 0; dd < 32; ++dd) {
      const int d = wv * 32 + dd;
      unsigned short* dst = vbase + (size_t)d * SEQ;
      dst[t]      = smem[t * 129 + d];
      dst[t + 64] = smem[(t + 64) * 129 + d];
    }
  }
}

// ---------------------------------------------------------------------------
// bf16 MFMA GEMM: C = A @ B, fp32 out (used for Wo).
// R12: same 3-buffer counted-vmcnt pipeline.
// ---------------------------------------------------------------------------
__global__ __launch_bounds__(256) void gemm_bf16_f32(const unsigned short* __restrict__ A,
                                                     const unsigned short* __restrict__ Bt,
                                                     float* __restrict__ C,
                                                     int M, int N, int K) {
  __shared__ unsigned short smem[3 * 8192];  // 48 KB staging (3 rotating pairs)

  const int tid = threadIdx.x;
  const int wave = tid >> 6;
  const int lane = tid & 63;
  const int bm = blockIdx.y * 128;
  const int bn = blockIdx.x * 128;
  const int wr = wave >> 1;
  const int wc = wave & 1;
  const int m15 = lane & 15;
  const int quad = lane >> 4;

  floatx4 acc[4][4];
#pragma unroll
  for (int i = 0; i < 4; ++i)
#pragma unroll
    for (int j = 0; j < 4; ++j) acc[i][j] = (floatx4){0.f, 0.f, 0.f, 0.f};

  const int srow = lane >> 2;
  const int scol = (((lane & 3) ^ ((lane >> 3) & 3))) * 8;

  unsigned short* c0 = smem;
  unsigned short* c1 = smem + 8192;
  unsigned short* c2 = smem + 16384;

  stage_tile4(A, Bt, c0, c0 + 4096, bm, bn, K, 0, wave, srow, scol);
  stage_tile4(A, Bt, c1, c1 + 4096, bm, bn, K, 32, wave, srow, scol);
  KLOOP_SYNC(true);

  const int NK = K >> 5;
  for (int t = 0; t < NK; ++t) {
    if (t + 2 < NK)
      stage_tile4(A, Bt, c2, c2 + 4096, bm, bn, K, (t + 2) * 32, wave, srow, scol);
    mfma_tile4(c0, c0 + 4096, acc, wr, wc, m15, quad);
    KLOOP_SYNC(t + 2 < NK);
    unsigned short* tmp = c0; c0 = c1; c1 = c2; c2 = tmp;
  }

#pragma unroll
  for (int i = 0; i < 4; ++i)
#pragma unroll
    for (int j = 0; j < 4; ++j) {
      const int col = bn + wc * 64 + j * 16 + m15;
#pragma unroll
      for (int reg = 0; reg < 4; ++reg) {
        const int row = bm + wr * 64 + i * 16 + quad * 4 + reg;
        C[(size_t)row * N + col] = acc[i][j][reg];
      }
    }
}

// ---------------------------------------------------------------------------
// MFMA flash attention (causal GQA), no-max softmax.
// |s| = |q.k|/16384 <= 128/16384 by Cauchy-Schwarz (rms-normed q,k, unit
// scales, norm-preserving RoPE) -> exp(s) can't overflow; no running max.
// Ps aliased over Ks (Ks dead after QK, Ps born after): LDS 42 -> 32 KB.
// __launch_bounds__(256, 4): VGPR cap 128 >= the ~68 this kernel needs ->
// 4 blocks/CU with NO spill.
// R8 lesson: (256,5) capped VGPR at ~102, allocator went to 48 and spilled
// acc_o to scratch (WRITE_SIZE 16->114 MB, 2.2x slower). R5 lesson: BM=128
// spills likewise. The live set (8 acc_o + 4 qf + 4 acc_s x4) needs ~128 cap.
// ---------------------------------------------------------------------------
__global__ __launch_bounds__(256, 4) void attn_mfma(const unsigned short* __restrict__ qb,
                                                    const unsigned short* __restrict__ kb,
                                                    const unsigned short* __restrict__ vtb,
                                                    unsigned short* __restrict__ o) {
  __shared__ unsigned short Ks[64 * 128];   // QK phase: K tile; PV phase: Ps (stride 72)
  __shared__ unsigned short Vs[128 * 64];
  unsigned short* Ps = Ks;

  const int tid = threadIdx.x;
  const int wave = tid >> 6;
  const int lane = tid & 63;
  const int m15 = lane & 15;
  const int quad = lane >> 4;
  const int bh = blockIdx.x;           // 0..31
  const int b = bh >> 4;
  const int h = bh & 15;
  const int g = h >> 2;
  const int q0 = ((int)gridDim.y - 1 - (int)blockIdx.y) * 64;  // longest first

  const unsigned short* qhead = qb + (size_t)bh * SEQ * 128;
  const unsigned short* khead = kb + (size_t)(b * NHK + g) * SEQ * 128;
  const unsigned short* vthead = vtb + (size_t)(b * NHK + g) * 128 * SEQ;

  short8 qf[4];
  {
    const unsigned short* qp = qhead + (size_t)(q0 + wave * 16 + m15) * 128 + quad * 8;
#pragma unroll
    for (int ks = 0; ks < 4; ++ks) qf[ks] = *(const short8*)(qp + ks * 32);
  }

  floatx4 acc_o[8];
#pragma unroll
  for (int n = 0; n < 8; ++n) acc_o[n] = (floatx4){0.f, 0.f, 0.f, 0.f};
  float l_lane[4] = {0.f, 0.f, 0.f, 0.f};
  const float inv_scale = 1.0f / 16384.0f;

  for (int j0 = 0; j0 <= q0; j0 += 64) {
    // ---- stage K tile (64 x 128, chunk-XOR swizzle) and Vt tile (128 x 64)
#pragma unroll
    for (int t = 0; t < 4; ++t) {
      const int r = wave * 16 + t * 4 + (lane >> 4);
      const int cg = (lane & 15) ^ (r & 15);
      const unsigned short* src = khead + (size_t)(j0 + r) * 128 + cg * 8;
      __builtin_amdgcn_global_load_lds(
          (const __attribute__((address_space(1))) void*)src,
          (__attribute__((address_space(3))) void*)&Ks[(wave * 16 + t * 4) * 128], 16, 0, 0);
    }
#pragma unroll
    for (int t = 0; t < 4; ++t) {
      const int d = wave * 32 + t * 8 + (lane >> 3);
      const int cg = (lane & 7) ^ (d & 7);
      const unsigned short* src = vthead + (size_t)d * SEQ + j0 + cg * 8;
      __builtin_amdgcn_global_load_lds(
          (const __attribute__((address_space(1))) void*)src,
          (__attribute__((address_space(3))) void*)&Vs[(wave * 32 + t * 8) * 64], 16, 0, 0);
    }
    __syncthreads();

    // ---- S = Q K^T
    floatx4 acc_s[4];
#pragma unroll
    for (int n = 0; n < 4; ++n) acc_s[n] = (floatx4){0.f, 0.f, 0.f, 0.f};
#pragma unroll
    for (int ks = 0; ks < 4; ++ks) {
#pragma unroll
      for (int n = 0; n < 4; ++n) {
        const short8 bfrag = *(const short8*)&Ks[(n * 16 + m15) * 128 + (((ks * 4 + quad) ^ m15) * 8)];
        acc_s[n] = __builtin_amdgcn_mfma_f32_16x16x32_bf16(qf[ks], bfrag, acc_s[n], 0, 0, 0);
      }
    }
    __syncthreads();   // all waves done reading Ks before Ps overwrites it

    // ---- p = exp(s/16384) -> Ps (over Ks region); mask only diagonal tile.
    if (j0 == q0) {
      const int row_g = wave * 16 + quad * 4;
#pragma unroll
      for (int n = 0; n < 4; ++n) {
        const int col = n * 16 + m15;
#pragma unroll
        for (int rg = 0; rg < 4; ++rg) {
          float p = (col > row_g + rg) ? 0.0f : __expf(acc_s[n][rg] * inv_scale);
          l_lane[rg] += p;
          Ps[(wave * 16 + quad * 4 + rg) * 72 + n * 16 + m15] = f2bf(p);
        }
      }
    } else {
#pragma unroll
      for (int n = 0; n < 4; ++n) {
#pragma unroll
        for (int rg = 0; rg < 4; ++rg) {
          const float p = __expf(acc_s[n][rg] * inv_scale);
          l_lane[rg] += p;
          Ps[(wave * 16 + quad * 4 + rg) * 72 + n * 16 + m15] = f2bf(p);
        }
      }
    }

    // ---- O += P V  (Ps rows wave-private: same-wave write->read, in-order)
#pragma unroll
    for (int kk = 0; kk < 2; ++kk) {
      const short8 a = *(const short8*)&Ps[(wave * 16 + m15) * 72 + kk * 32 + quad * 8];
#pragma unroll
      for (int n = 0; n < 8; ++n) {
        const short8 bfrag = *(const short8*)&Vs[(n * 16 + m15) * 64 + (((kk * 4 + quad) ^ (m15 & 7)) * 8)];
        acc_o[n] = __builtin_amdgcn_mfma_f32_16x16x32_bf16(a, bfrag, acc_o[n], 0, 0, 0);
      }
    }
    __syncthreads();   // Ps reads done before next iteration restages Ks
  }

#pragma unroll
  for (int rg = 0; rg < 4; ++rg) {
    float l = l_lane[rg];
    l += __shfl_xor(l, 1);
    l += __shfl_xor(l, 2);
    l += __shfl_xor(l, 4);
    l += __shfl_xor(l, 8);
    const float invl = 1.0f / l;
    const size_t row = (size_t)(b * SEQ + q0 + wave * 16 + quad * 4 + rg);
#pragma unroll
    for (int n = 0; n < 8; ++n)
      o[row * DMODEL + h * 128 + n * 16 + m15] = f2bf(acc_o[n][rg] * invl);
  }
}

// ---------------------------------------------------------------------------
extern "C" void kernel_launch(void* const* d_in, const int* in_sizes, int n_in,
                              void* d_out, int out_size, void* d_ws, size_t ws_size,
                              hipStream_t stream) {
  const float* x       = (const float*)d_in[0];
  const float* Wq      = (const float*)d_in[1];
  const float* Wk      = (const float*)d_in[2];
  const float* Wv      = (const float*)d_in[3];
  const float* Wo      = (const float*)d_in[4];
  const float* q_scale = (const float*)d_in[5];
  const float* k_scale = (const float*)d_in[6];
  const float* cosb    = (const float*)d_in[7];
  const float* sinb    = (const float*)d_in[8];
  float* out = (float*)d_out;

  // Workspace (79.69 MB, no overlays; 83.9 MB proven available):
  char* w = (char*)d_ws;
  unsigned short* x_bf    = (unsigned short*)w;               // [0, 16.78M)
  unsigned short* wqkv_t  = (unsigned short*)(w + 16777216);  // [16.78M, 29.36M)
  unsigned short* q_bf    = (unsigned short*)(w + 29360128);  // [29.36M, 46.14M)
  unsigned short* k_bf    = (unsigned short*)(w + 46137344);  // [46.14M, 50.33M)
  unsigned short* vt      = (unsigned short*)(w + 50331648);  // [50.33M, 54.53M)
  unsigned short* wo_t    = (unsigned short*)(w + 54525952);  // [54.53M, 62.91M)
  unsigned short* attn_bf = (unsigned short*)(w + 62914560);  // [62.91M, 79.69M)

  // One prep launch: cast x + all weight transposes (64-row tiles).
  prep<<<dim3(64, 32, 4), dim3(32, 8), 0, stream>>>(x, Wq, Wk, Wv, Wo, x_bf, wqkv_t, wo_t);

  // Fused QKV projection + RMSNorm + RoPE + V-transpose (3-buf counted vmcnt).
  gemm_qkv_fused<<<dim3(24, 32), 256, 0, stream>>>(x_bf, wqkv_t, q_bf, k_bf, vt,
                                                   q_scale, k_scale, cosb, sinb);

  // Attention, then output projection (3-buf counted vmcnt).
  attn_mfma<<<dim3(2 * NHQ, SEQ / 64), 256, 0, stream>>>(q_bf, k_bf, vt, attn_bf);
  gemm_bf16_f32<<<dim3(2048 / 128, 4096 / 128), 256, 0, stream>>>(
      attn_bf, wo_t, out, 4096, 2048, 2048);
}